// Round 17
// baseline (14.219 us; speedup 1.0000x reference)
//
#include <hip/hip_runtime.h>
#include <hip/hip_bf16.h>

#define T_LEN 16384
#define O_CH 64
#define I_CH 64
#define NB 16
#define NA 15
#define L_TAPS 32            // taps >=32 are O(a^2): out-err ~1.5e-6 std. Proven free (R13).
#define TBLK 256             // t-rows per block
#define HALO 32              // >= L_TAPS-1, multiple of 8 (keeps XOR swizzle row phase)

typedef __attribute__((ext_vector_type(8))) short short8;     // 8 bf16 = 4 VGPR (MFMA A/B frag)
typedef __attribute__((ext_vector_type(4))) float f32x4;      // MFMA C/D frag / vector load

// ============ single fused kernel: in-LDS G-slice + implicit-Hankel GEMM ============
// R16 structure (proven 13.9 us) + two latency fixes:
//  (a) T14 split: ALL global loads (u + coeffs) issued at kernel top; u convert/write
//      consumes the early loads while coeff loads complete under it; G recurrence after.
//  (b) main loop: 1-step double-buffered af/bf frag reads (static idx under unroll).
// Grid: dim3(64, 4) = 256 blocks = 1/CU. Block: 1024 thr = 16 waves = 4 waves/SIMD.
// Block owns out rows [T0,T0+256) x cols [O0,O0+16); B-slice computed in-block to LDS.
__global__ __launch_bounds__(1024, 4) void k_fused(const float* __restrict__ u,
                                                   const float* __restrict__ b_coeff,
                                                   const float* __restrict__ a_coeff,
                                                   float* __restrict__ out)
{
    __shared__ __align__(16) unsigned char lds_u[(TBLK + HALO) * 128];   // 36 KB u plane
    __shared__ __align__(16) unsigned char lds_g[64 * 1024];             // 64 KB G-slice; reduce buf later
    const int tid = threadIdx.x, lane = tid & 63, w = tid >> 6;
    const int mq = w & 3, ihw = (w >> 2) & 1, th = w >> 3;
    const int T0 = blockIdx.x * TBLK;
    const int O0 = blockIdx.y * 16;

    // ---- phase 0: issue ALL global loads up front (T14 issue-early) ----
    f32x4 va[3], vb[3];
    #pragma unroll
    for (int c = 0; c < 3; ++c) {
        const int idx = c * 1024 + tid;          // (TBLK+HALO)*8 = 2304 16B-chunks
        const int row = idx >> 3, c16 = idx & 7;
        const int t = T0 - HALO + row;
        va[c] = (f32x4){0.f, 0.f, 0.f, 0.f};
        vb[c] = (f32x4){0.f, 0.f, 0.f, 0.f};
        if (idx < (TBLK + HALO) * 8 && t >= 0) {
            const f32x4* s4 = (const f32x4*)(u + (size_t)t * 64 + c16 * 8);
            va[c] = s4[0]; vb[c] = s4[1];
        }
    }
    const int o_loc = tid >> 6, ii = tid & 63;
    const int p = (O0 + o_loc) * 64 + ii;
    float bcv[NB], acv[NA];
    #pragma unroll
    for (int k = 0; k < NB; ++k) bcv[k] = b_coeff[p * NB + k];
    #pragma unroll
    for (int k = 0; k < NA; ++k) acv[k] = a_coeff[p * NA + k];

    // ---- phase 1: u convert + LDS write (earliest loads; coeffs still in flight) ----
    union BU { __hip_bfloat16 b; unsigned short s; };
    #pragma unroll
    for (int c = 0; c < 3; ++c) {
        const int idx = c * 1024 + tid;
        if (idx < (TBLK + HALO) * 8) {
            const int row = idx >> 3, c16 = idx & 7;
            short8 h8;
            #pragma unroll
            for (int e = 0; e < 8; ++e) {
                const float x = (e < 4) ? va[c][e] : vb[c][e - 4];
                BU hb; hb.b = __float2bfloat16(x);
                h8[e] = (short)hb.s;
            }
            *(short8*)(lds_u + row * 128 + ((c16 ^ (row & 7)) << 4)) = h8;
        }
    }

    // ---- phase 2: G recurrence (VALU) + scatter to LDS B-frag layout ----
    {
        float h[L_TAPS];
        #pragma unroll
        for (int n = 0; n < L_TAPS; ++n) {
            float s0 = (n < NB) ? bcv[n] : 0.0f, s1 = 0.0f, s2 = 0.0f, s3 = 0.0f;
            #pragma unroll
            for (int k = 0; k < NA; ++k) {
                if (n - 1 - k >= 0) {
                    const float t = -acv[k] * h[n - 1 - k];
                    if ((k & 3) == 0) s0 += t;
                    else if ((k & 3) == 1) s1 += t;
                    else if ((k & 3) == 2) s2 += t;
                    else s3 += t;
                }
            }
            h[n] = (s0 + s1) + (s2 + s3);
        }
        const int ih = ii >> 5, kl = ii & 31;
        const int lane_g = ((kl >> 3) << 4) | o_loc, e = kl & 7;
        const unsigned base = (unsigned)(lane_g * 16 + e * 2);
        #pragma unroll
        for (int n = 0; n < L_TAPS; ++n) {
            __hip_bfloat16 g = __float2bfloat16(h[n] * (1.0f / 64.0f));
            *(__hip_bfloat16*)(lds_g + base + (unsigned)((n * 2 + ih) * 1024)) = g;
        }
    }
    __syncthreads();                       // u plane + G-slice staged

    // ---- phase 3: MFMA main loop, 1-step double-buffered frag reads ----
    const int rbase = HALO + 64 * mq + (lane & 15);
    const int c16a  = ihw * 4 + (lane >> 4);
    const int tlb   = 8 * th;

    auto load_frags = [&](short8 (&af)[5], short8 (&bf)[2], int tl) {
        bf[0] = *(const short8*)(lds_g + ((tl * 2        + ihw) << 10) + lane * 16);
        bf[1] = *(const short8*)(lds_g + (((tl + 16) * 2 + ihw) << 10) + lane * 16);
        #pragma unroll
        for (int j = 0; j < 5; ++j) {       // j = mt - tq + 1 in [0,4]
            const int lrow = rbase - tl + 16 * j - 16;
            af[j] = *(const short8*)(lds_u + lrow * 128 + ((c16a ^ (lrow & 7)) << 4));
        }
    };

    short8 afb[2][5], bfb[2][2];
    load_frags(afb[0], bfb[0], tlb);

    f32x4 acc[4];
    #pragma unroll
    for (int mt = 0; mt < 4; ++mt) acc[mt] = (f32x4){0.f, 0.f, 0.f, 0.f};

    #pragma unroll
    for (int tl8 = 0; tl8 < 8; ++tl8) {
        const int cur = tl8 & 1;
        if (tl8 < 7) load_frags(afb[cur ^ 1], bfb[cur ^ 1], tlb + tl8 + 1);
        #pragma unroll
        for (int tq = 0; tq < 2; ++tq)
            #pragma unroll
            for (int mt = 0; mt < 4; ++mt)
                acc[mt] = __builtin_amdgcn_mfma_f32_16x16x32_bf16(
                    afb[cur][mt - tq + 1], bfb[cur][tq], acc[mt], 0, 0, 0);
    }

    // ---- phase 4: 4-part reduce (part = w>>2, reuse lds_g as f32x4 buf), store ----
    const int part = w >> 2;               // 0..3; part 0 sums and stores
    __syncthreads();                       // all lds_u/lds_g reads done
    if (part != 0) {
        #pragma unroll
        for (int mt = 0; mt < 4; ++mt)
            *(f32x4*)(lds_g + ((((part - 1) * 16 + mq * 4 + mt) * 64 + lane) << 4)) = acc[mt];
    }
    __syncthreads();
    if (part == 0) {
        #pragma unroll
        for (int mt = 0; mt < 4; ++mt) {
            f32x4 v = acc[mt];
            #pragma unroll
            for (int pp = 0; pp < 3; ++pp)
                v += *(const f32x4*)(lds_g + (((pp * 16 + mq * 4 + mt) * 64 + lane) << 4));
            #pragma unroll
            for (int q = 0; q < 4; ++q) {
                const int row = T0 + 64 * mq + 16 * mt + (lane >> 4) * 4 + q;  // m89 C/D map
                const int col = O0 + (lane & 15);
                out[(size_t)row * 64 + col] = v[q];
            }
        }
    }
}

extern "C" void kernel_launch(void* const* d_in, const int* in_sizes, int n_in,
                              void* d_out, int out_size, void* d_ws, size_t ws_size,
                              hipStream_t stream) {
    const float* u = (const float*)d_in[0];
    const float* b = (const float*)d_in[1];
    const float* a = (const float*)d_in[2];
    float* out = (float*)d_out;

    dim3 grid(T_LEN / TBLK, O_CH / 16);    // 64 x 4 = 256 blocks = 1/CU
    k_fused<<<grid, 1024, 0, stream>>>(u, b, a, out);
}